// Round 2
// baseline (1474.928 us; speedup 1.0000x reference)
//
#include <hip/hip_runtime.h>
#include <hip/hip_bf16.h>
#include <stdint.h>

#define N_NODES 100000
#define N_EDGES 1000000
#define N_GRAPHS 512
#define HID 64
#define INN 32
#define INE 16

// ---------------- diag ----------------

__global__ void k_diag(float* out, float val) { out[threadIdx.x] = val; }

// ---------------- CSR build ----------------

__global__ void k_hist(const int* __restrict__ dst, int* __restrict__ counts) {
    int e = blockIdx.x * 256 + threadIdx.x;
    if (e < N_EDGES) atomicAdd(&counts[dst[e]], 1);
}

__global__ void k_scan1(const int* __restrict__ counts, int* __restrict__ bsums) {
    __shared__ int sdata[256];
    int b = blockIdx.x;
    int s = 0;
    for (int j = threadIdx.x; j < 1024; j += 256) {
        int i = b * 1024 + j;
        s += (i < N_NODES) ? counts[i] : 0;
    }
    sdata[threadIdx.x] = s; __syncthreads();
    for (int off = 128; off > 0; off >>= 1) {
        if (threadIdx.x < off) sdata[threadIdx.x] += sdata[threadIdx.x + off];
        __syncthreads();
    }
    if (threadIdx.x == 0) bsums[b] = sdata[0];
}

__global__ void k_scan2(int* __restrict__ bsums, int nb) {
    __shared__ int sh[128];
    int v = (threadIdx.x < nb) ? bsums[threadIdx.x] : 0;
    sh[threadIdx.x] = v; __syncthreads();
    for (int off = 1; off < 128; off <<= 1) {
        int t = (threadIdx.x >= off) ? sh[threadIdx.x - off] : 0;
        __syncthreads();
        sh[threadIdx.x] += t;
        __syncthreads();
    }
    if (threadIdx.x < nb) bsums[threadIdx.x] = sh[threadIdx.x] - v;  // exclusive
}

__global__ void k_scan3(const int* __restrict__ counts, const int* __restrict__ bsums,
                        int* __restrict__ rowptr, int* __restrict__ cursor) {
    __shared__ int sh[256];
    int b = blockIdx.x;
    int base = b * 1024;
    int v[4]; int s = 0;
    #pragma unroll
    for (int j = 0; j < 4; j++) {
        int i = base + threadIdx.x * 4 + j;
        v[j] = (i < N_NODES) ? counts[i] : 0;
        s += v[j];
    }
    sh[threadIdx.x] = s; __syncthreads();
    for (int off = 1; off < 256; off <<= 1) {
        int t = (threadIdx.x >= off) ? sh[threadIdx.x - off] : 0;
        __syncthreads();
        sh[threadIdx.x] += t;
        __syncthreads();
    }
    int excl = sh[threadIdx.x] - s + bsums[b];
    #pragma unroll
    for (int j = 0; j < 4; j++) {
        int i = base + threadIdx.x * 4 + j;
        if (i < N_NODES) { rowptr[i] = excl; cursor[i] = excl; excl += v[j]; }
    }
    if (b == gridDim.x - 1 && threadIdx.x == 255) rowptr[N_NODES] = excl;
}

__global__ void k_fill(const int* __restrict__ src, const int* __restrict__ dst,
                       int* __restrict__ cursor, int* __restrict__ perm_src,
                       int* __restrict__ perm_eid) {
    int e = blockIdx.x * 256 + threadIdx.x;
    if (e < N_EDGES) {
        int d = dst[e];
        int p = atomicAdd(&cursor[d], 1);
        perm_src[p] = src[e];
        perm_eid[p] = e;
    }
}

// ---------------- weight transposes ----------------

struct TransJob { const float* w; float* wt; int K; int C; };
struct TransJobs { TransJob j[12]; };

__global__ void k_transpose_all(TransJobs jobs) {
    TransJob t = jobs.j[blockIdx.x];
    int n = t.K * t.C;
    for (int i = threadIdx.x; i < n; i += 256) {
        int k = i / t.C, c = i % t.C;
        t.wt[c * t.K + k] = t.w[i];
    }
}

// ---------------- node-side MLP2 (lane = row) ----------------
// out = RELU_RES ? relu(hprev + MLP2(in)) : MLP2(in)

template<int K0, bool RELU_RES>
__global__ __launch_bounds__(256) void k_mlp(
    const float* __restrict__ in, const float* __restrict__ hprev, float* __restrict__ out,
    const float* __restrict__ w0t, const float* __restrict__ b0,
    const float* __restrict__ w1t, const float* __restrict__ b1, int nrows)
{
    int r = blockIdx.x * 256 + threadIdx.x;
    int rr = (r < nrows) ? r : (nrows - 1);
    float a[K0];
    {
        const float4* p = (const float4*)(in + (size_t)rr * K0);
        #pragma unroll
        for (int j = 0; j < K0 / 4; j++) {
            float4 v = p[j];
            a[4*j+0]=v.x; a[4*j+1]=v.y; a[4*j+2]=v.z; a[4*j+3]=v.w;
        }
    }
    float t1[HID];
    #pragma unroll 1
    for (int c4 = 0; c4 < HID/4; c4++) {
        float acc0 = b0[c4*4+0], acc1 = b0[c4*4+1], acc2 = b0[c4*4+2], acc3 = b0[c4*4+3];
        #pragma unroll
        for (int k = 0; k < K0; k++) {
            float av = a[k];
            acc0 = fmaf(av, w0t[(c4*4+0)*K0 + k], acc0);
            acc1 = fmaf(av, w0t[(c4*4+1)*K0 + k], acc1);
            acc2 = fmaf(av, w0t[(c4*4+2)*K0 + k], acc2);
            acc3 = fmaf(av, w0t[(c4*4+3)*K0 + k], acc3);
        }
        t1[c4*4+0] = fmaxf(acc0, 0.f);
        t1[c4*4+1] = fmaxf(acc1, 0.f);
        t1[c4*4+2] = fmaxf(acc2, 0.f);
        t1[c4*4+3] = fmaxf(acc3, 0.f);
    }
    float4* op = (float4*)(out + (size_t)rr * HID);
    const float4* hp = (const float4*)(RELU_RES ? (hprev + (size_t)rr * HID) : nullptr);
    #pragma unroll 1
    for (int c4 = 0; c4 < HID/4; c4++) {
        float acc0 = b1[c4*4+0], acc1 = b1[c4*4+1], acc2 = b1[c4*4+2], acc3 = b1[c4*4+3];
        #pragma unroll
        for (int k = 0; k < HID; k++) {
            float tv = t1[k];
            acc0 = fmaf(tv, w1t[(c4*4+0)*HID + k], acc0);
            acc1 = fmaf(tv, w1t[(c4*4+1)*HID + k], acc1);
            acc2 = fmaf(tv, w1t[(c4*4+2)*HID + k], acc2);
            acc3 = fmaf(tv, w1t[(c4*4+3)*HID + k], acc3);
        }
        float4 res;
        res.x = acc0; res.y = acc1; res.z = acc2; res.w = acc3;
        if (RELU_RES) {
            float4 h4 = hp[c4];
            res.x = fmaxf(res.x + h4.x, 0.f);
            res.y = fmaxf(res.y + h4.y, 0.f);
            res.z = fmaxf(res.z + h4.z, 0.f);
            res.w = fmaxf(res.w + h4.w, 0.f);
        }
        if (r < nrows) op[c4] = res;
    }
}

// ---------------- edge MLP2 (lane = edge), writes dst-sorted e (bf16) ----------------

__global__ __launch_bounds__(128) void k_edge_mlp(
    const float* __restrict__ eattr, const int* __restrict__ perm_eid,
    __hip_bfloat16* __restrict__ e_sorted,
    const float* __restrict__ w0t, const float* __restrict__ b0,
    const float* __restrict__ w1t, const float* __restrict__ b1)
{
    __shared__ float tile[2][64 * 65];
    int wave = threadIdx.x >> 6, lane = threadIdx.x & 63;
    size_t p = (size_t)blockIdx.x * 128 + threadIdx.x;
    int eid = (p < N_EDGES) ? perm_eid[p] : 0;
    float a[INE];
    {
        const float4* pr = (const float4*)(eattr + (size_t)eid * INE);
        #pragma unroll
        for (int j = 0; j < INE/4; j++) {
            float4 v = pr[j];
            a[4*j+0]=v.x; a[4*j+1]=v.y; a[4*j+2]=v.z; a[4*j+3]=v.w;
        }
    }
    float t1[HID];
    #pragma unroll 1
    for (int c4 = 0; c4 < HID/4; c4++) {
        float acc0 = b0[c4*4+0], acc1 = b0[c4*4+1], acc2 = b0[c4*4+2], acc3 = b0[c4*4+3];
        #pragma unroll
        for (int k = 0; k < INE; k++) {
            float av = a[k];
            acc0 = fmaf(av, w0t[(c4*4+0)*INE + k], acc0);
            acc1 = fmaf(av, w0t[(c4*4+1)*INE + k], acc1);
            acc2 = fmaf(av, w0t[(c4*4+2)*INE + k], acc2);
            acc3 = fmaf(av, w0t[(c4*4+3)*INE + k], acc3);
        }
        t1[c4*4+0] = fmaxf(acc0, 0.f);
        t1[c4*4+1] = fmaxf(acc1, 0.f);
        t1[c4*4+2] = fmaxf(acc2, 0.f);
        t1[c4*4+3] = fmaxf(acc3, 0.f);
    }
    float* my = &tile[wave][lane * 65];
    #pragma unroll 1
    for (int c4 = 0; c4 < HID/4; c4++) {
        float acc0 = b1[c4*4+0], acc1 = b1[c4*4+1], acc2 = b1[c4*4+2], acc3 = b1[c4*4+3];
        #pragma unroll
        for (int k = 0; k < HID; k++) {
            float tv = t1[k];
            acc0 = fmaf(tv, w1t[(c4*4+0)*HID + k], acc0);
            acc1 = fmaf(tv, w1t[(c4*4+1)*HID + k], acc1);
            acc2 = fmaf(tv, w1t[(c4*4+2)*HID + k], acc2);
            acc3 = fmaf(tv, w1t[(c4*4+3)*HID + k], acc3);
        }
        my[c4*4+0] = acc0; my[c4*4+1] = acc1; my[c4*4+2] = acc2; my[c4*4+3] = acc3;
    }
    __syncthreads();
    // coalesced flush: row r = edge (waveBase + r), channel = lane; f32 -> bf16
    size_t waveBase = (size_t)blockIdx.x * 128 + (size_t)wave * 64;
    for (int rr = 0; rr < 64; rr++) {
        size_t pos = waveBase + rr;
        if (pos < N_EDGES)
            e_sorted[pos * HID + lane] = __float2bfloat16(tile[wave][rr * 65 + lane]);
    }
}

// ---------------- GINE aggregation: z = sum relu(h[src]+e) + 1.1*h ----------------

__global__ __launch_bounds__(256) void k_agg(
    const float* __restrict__ h, const __hip_bfloat16* __restrict__ e_sorted,
    const int* __restrict__ rowptr, const int* __restrict__ perm_src,
    float* __restrict__ z)
{
    int node = blockIdx.x * 4 + (threadIdx.x >> 6);
    if (node >= N_NODES) return;
    int lane = threadIdx.x & 63;
    int r0 = rowptr[node], r1 = rowptr[node + 1];
    float acc = 0.f;
    int p = r0;
    for (; p + 4 <= r1; p += 4) {
        int s0 = perm_src[p+0], s1 = perm_src[p+1], s2 = perm_src[p+2], s3 = perm_src[p+3];
        float h0 = h[(size_t)s0*HID + lane], h1 = h[(size_t)s1*HID + lane];
        float h2 = h[(size_t)s2*HID + lane], h3 = h[(size_t)s3*HID + lane];
        float e0 = __bfloat162float(e_sorted[(size_t)(p+0)*HID + lane]);
        float e1 = __bfloat162float(e_sorted[(size_t)(p+1)*HID + lane]);
        float e2 = __bfloat162float(e_sorted[(size_t)(p+2)*HID + lane]);
        float e3 = __bfloat162float(e_sorted[(size_t)(p+3)*HID + lane]);
        acc += fmaxf(h0 + e0, 0.f);
        acc += fmaxf(h1 + e1, 0.f);
        acc += fmaxf(h2 + e2, 0.f);
        acc += fmaxf(h3 + e3, 0.f);
    }
    for (; p < r1; ++p) {
        float hv = h[(size_t)perm_src[p]*HID + lane];
        float ev = __bfloat162float(e_sorted[(size_t)p*HID + lane]);
        acc += fmaxf(hv + ev, 0.f);
    }
    z[(size_t)node*HID + lane] = fmaf(1.1f, h[(size_t)node*HID + lane], acc);
}

// ---------------- global add pool (batch is sorted) ----------------

__global__ __launch_bounds__(256) void k_pool(
    const float* __restrict__ h, const int* __restrict__ batch, float* __restrict__ out)
{
    int g = blockIdx.x;
    int lane = threadIdx.x & 63, wave = threadIdx.x >> 6;
    int lo = 0, hi = N_NODES;
    while (lo < hi) { int mid = (lo + hi) >> 1; if (batch[mid] < g) lo = mid + 1; else hi = mid; }
    int start = lo;
    hi = N_NODES;
    while (lo < hi) { int mid = (lo + hi) >> 1; if (batch[mid] < g + 1) lo = mid + 1; else hi = mid; }
    int end = lo;
    float acc = 0.f;
    for (int n = start + wave; n < end; n += 4)
        acc += h[(size_t)n*HID + lane];
    __shared__ float sh[4][64];
    sh[wave][lane] = acc;
    __syncthreads();
    if (wave == 0)
        out[(size_t)g*HID + lane] = sh[0][lane] + sh[1][lane] + sh[2][lane] + sh[3][lane];
}

// ---------------- launch ----------------

extern "C" void kernel_launch(void* const* d_in, const int* in_sizes, int n_in,
                              void* d_out, int out_size, void* d_ws, size_t ws_size,
                              hipStream_t stream) {
    const float* x     = (const float*)d_in[0];
    const int*   eidx  = (const int*)  d_in[1];
    const float* eattr = (const float*)d_in[2];
    const int*   batch = (const int*)  d_in[3];
    const float* wn0 = (const float*)d_in[4];  const float* bn0 = (const float*)d_in[5];
    const float* wn1 = (const float*)d_in[6];  const float* bn1 = (const float*)d_in[7];
    const float* we0 = (const float*)d_in[8];  const float* be0 = (const float*)d_in[9];
    const float* we1 = (const float*)d_in[10]; const float* be1 = (const float*)d_in[11];
    const float* cw0 = (const float*)d_in[12]; const float* cb0 = (const float*)d_in[13];
    const float* cw1 = (const float*)d_in[14]; const float* cb1 = (const float*)d_in[15];
    const float* lw0 = (const float*)d_in[16]; const float* lb0 = (const float*)d_in[17];
    const float* lw1 = (const float*)d_in[18]; const float* lb1 = (const float*)d_in[19];
    const int* src = eidx;
    const int* dst = eidx + N_EDGES;

    // workspace layout (~214 MB)
    char* ws = (char*)d_ws;
    size_t off = 0;
    auto alloc = [&](size_t bytes) -> void* {
        void* p = ws + off;
        off = (off + bytes + 255) & ~(size_t)255;
        return p;
    };
    int*   counts   = (int*)  alloc((size_t)N_NODES * 4);
    int*   rowptr   = (int*)  alloc((size_t)(N_NODES + 1) * 4);
    int*   cursor   = (int*)  alloc((size_t)N_NODES * 4);
    int*   bsums    = (int*)  alloc(128 * 4);
    int*   perm_src = (int*)  alloc((size_t)N_EDGES * 4);
    int*   perm_eid = (int*)  alloc((size_t)N_EDGES * 4);
    float* wt       = (float*)alloc((size_t)44032 * 4);
    float* hA       = (float*)alloc((size_t)N_NODES * HID * 4);
    float* hB       = (float*)alloc((size_t)N_NODES * HID * 4);
    float* zbuf     = (float*)alloc((size_t)N_NODES * HID * 4);
    __hip_bfloat16* e_sorted = (__hip_bfloat16*)alloc((size_t)N_EDGES * HID * 2);
    if (off > ws_size) {
        // distinctive signature: absmax ~= 1e9 means "workspace too small"
        k_diag<<<1, 64, 0, stream>>>((float*)d_out, 1.0e9f);
        return;
    }

    // transposed weight offsets (floats)
    float* wn0t = wt + 0;
    float* wn1t = wt + 2048;
    float* we0t = wt + 6144;
    float* we1t = wt + 7168;
    float* cw0t = wt + 11264;   // 3 * 4096
    float* cw1t = wt + 23552;   // 3 * 4096
    float* lw0t = wt + 35840;
    float* lw1t = wt + 39936;

    const int NB = (N_NODES + 1023) / 1024;  // 98

    hipMemsetAsync(counts, 0, (size_t)N_NODES * 4, stream);
    k_hist<<<(N_EDGES + 255) / 256, 256, 0, stream>>>(dst, counts);
    k_scan1<<<NB, 256, 0, stream>>>(counts, bsums);
    k_scan2<<<1, 128, 0, stream>>>(bsums, NB);
    k_scan3<<<NB, 256, 0, stream>>>(counts, bsums, rowptr, cursor);
    k_fill<<<(N_EDGES + 255) / 256, 256, 0, stream>>>(src, dst, cursor, perm_src, perm_eid);

    TransJobs jobs;
    jobs.j[0]  = { wn0, wn0t, INN, HID };
    jobs.j[1]  = { wn1, wn1t, HID, HID };
    jobs.j[2]  = { we0, we0t, INE, HID };
    jobs.j[3]  = { we1, we1t, HID, HID };
    for (int l = 0; l < 3; l++) {
        jobs.j[4 + l] = { cw0 + l * 4096, cw0t + l * 4096, HID, HID };
        jobs.j[7 + l] = { cw1 + l * 4096, cw1t + l * 4096, HID, HID };
    }
    jobs.j[10] = { lw0, lw0t, HID, HID };
    jobs.j[11] = { lw1, lw1t, HID, HID };
    k_transpose_all<<<12, 256, 0, stream>>>(jobs);

    const int NGRID = (N_NODES + 255) / 256;  // 391

    // node init MLP: x -> hA
    k_mlp<INN, false><<<NGRID, 256, 0, stream>>>(x, nullptr, hA, wn0t, bn0, wn1t, bn1, N_NODES);

    // edge MLP -> e_sorted (dst-sorted order, bf16)
    k_edge_mlp<<<(N_EDGES + 127) / 128, 128, 0, stream>>>(eattr, perm_eid, e_sorted,
                                                          we0t, be0, we1t, be1);

    float* hcur = hA;
    float* hnxt = hB;
    const int AGRID = (N_NODES + 3) / 4;  // 25000
    for (int l = 0; l < 3; l++) {
        k_agg<<<AGRID, 256, 0, stream>>>(hcur, e_sorted, rowptr, perm_src, zbuf);
        k_mlp<HID, true><<<NGRID, 256, 0, stream>>>(zbuf, hcur, hnxt,
                                                    cw0t + l * 4096, cb0 + l * 64,
                                                    cw1t + l * 4096, cb1 + l * 64, N_NODES);
        float* t = hcur; hcur = hnxt; hnxt = t;
    }
    // final GINE conv (no residual/relu)
    k_agg<<<AGRID, 256, 0, stream>>>(hcur, e_sorted, rowptr, perm_src, zbuf);
    k_mlp<HID, false><<<NGRID, 256, 0, stream>>>(zbuf, nullptr, hnxt,
                                                 lw0t, lb0, lw1t, lb1, N_NODES);

    // global add pool
    k_pool<<<N_GRAPHS, 256, 0, stream>>>(hnxt, batch, (float*)d_out);
}

// Round 3
// 1358.823 us; speedup vs baseline: 1.0854x; 1.0854x over previous
//
#include <hip/hip_runtime.h>
#include <hip/hip_bf16.h>
#include <stdint.h>

#define N_NODES 100000
#define N_EDGES 1000000
#define N_GRAPHS 512
#define HID 64
#define INN 32
#define INE 16

typedef unsigned int uint32;
typedef unsigned short ushort16;

__device__ __forceinline__ ushort16 f2bf(float f) {
    uint32 u = __float_as_uint(f);
    uint32 r = (u + 0x7fffu + ((u >> 16) & 1u)) >> 16;  // RNE
    return (ushort16)r;
}
__device__ __forceinline__ uint32 pack_bf2(float lo, float hi) {
    return (uint32)f2bf(lo) | ((uint32)f2bf(hi) << 16);
}
__device__ __forceinline__ float bf_lo(uint32 v) { return __uint_as_float(v << 16); }
__device__ __forceinline__ float bf_hi(uint32 v) { return __uint_as_float(v & 0xffff0000u); }

// ---------------- diag ----------------

__global__ void k_diag(float* out, float val) { out[threadIdx.x] = val; }

// ---------------- CSR build ----------------

__global__ void k_hist(const int* __restrict__ dst, int* __restrict__ counts) {
    int e = blockIdx.x * 256 + threadIdx.x;
    if (e < N_EDGES) atomicAdd(&counts[dst[e]], 1);
}

__global__ void k_scan1(const int* __restrict__ counts, int* __restrict__ bsums) {
    __shared__ int sdata[256];
    int b = blockIdx.x;
    int s = 0;
    for (int j = threadIdx.x; j < 1024; j += 256) {
        int i = b * 1024 + j;
        s += (i < N_NODES) ? counts[i] : 0;
    }
    sdata[threadIdx.x] = s; __syncthreads();
    for (int off = 128; off > 0; off >>= 1) {
        if (threadIdx.x < off) sdata[threadIdx.x] += sdata[threadIdx.x + off];
        __syncthreads();
    }
    if (threadIdx.x == 0) bsums[b] = sdata[0];
}

__global__ void k_scan2(int* __restrict__ bsums, int nb) {
    __shared__ int sh[128];
    int v = (threadIdx.x < nb) ? bsums[threadIdx.x] : 0;
    sh[threadIdx.x] = v; __syncthreads();
    for (int off = 1; off < 128; off <<= 1) {
        int t = (threadIdx.x >= off) ? sh[threadIdx.x - off] : 0;
        __syncthreads();
        sh[threadIdx.x] += t;
        __syncthreads();
    }
    if (threadIdx.x < nb) bsums[threadIdx.x] = sh[threadIdx.x] - v;  // exclusive
}

__global__ void k_scan3(const int* __restrict__ counts, const int* __restrict__ bsums,
                        int* __restrict__ rowptr, int* __restrict__ cursor) {
    __shared__ int sh[256];
    int b = blockIdx.x;
    int base = b * 1024;
    int v[4]; int s = 0;
    #pragma unroll
    for (int j = 0; j < 4; j++) {
        int i = base + threadIdx.x * 4 + j;
        v[j] = (i < N_NODES) ? counts[i] : 0;
        s += v[j];
    }
    sh[threadIdx.x] = s; __syncthreads();
    for (int off = 1; off < 256; off <<= 1) {
        int t = (threadIdx.x >= off) ? sh[threadIdx.x - off] : 0;
        __syncthreads();
        sh[threadIdx.x] += t;
        __syncthreads();
    }
    int excl = sh[threadIdx.x] - s + bsums[b];
    #pragma unroll
    for (int j = 0; j < 4; j++) {
        int i = base + threadIdx.x * 4 + j;
        if (i < N_NODES) { rowptr[i] = excl; cursor[i] = excl; excl += v[j]; }
    }
    if (b == gridDim.x - 1 && threadIdx.x == 255) rowptr[N_NODES] = excl;
}

// newpos[e] = slot of edge e in the dst-sorted order (inverse permutation)
__global__ void k_fill(const int* __restrict__ src, const int* __restrict__ dst,
                       int* __restrict__ cursor, int* __restrict__ perm_src,
                       int* __restrict__ newpos) {
    int e = blockIdx.x * 256 + threadIdx.x;
    if (e < N_EDGES) {
        int d = dst[e];
        int p = atomicAdd(&cursor[d], 1);
        perm_src[p] = src[e];
        newpos[e] = p;
    }
}

// ---------------- weight transposes ----------------

struct TransJob { const float* w; float* wt; int K; int C; };
struct TransJobs { TransJob j[12]; };

__global__ void k_transpose_all(TransJobs jobs) {
    TransJob t = jobs.j[blockIdx.x];
    int n = t.K * t.C;
    for (int i = threadIdx.x; i < n; i += 256) {
        int k = i / t.C, c = i % t.C;
        t.wt[c * t.K + k] = t.w[i];
    }
}

// ---------------- node-side MLP2 (lane = row) ----------------

template<int K0, bool RELU_RES>
__global__ __launch_bounds__(256) void k_mlp(
    const float* __restrict__ in, const float* __restrict__ hprev, float* __restrict__ out,
    const float* __restrict__ w0t, const float* __restrict__ b0,
    const float* __restrict__ w1t, const float* __restrict__ b1, int nrows)
{
    int r = blockIdx.x * 256 + threadIdx.x;
    int rr = (r < nrows) ? r : (nrows - 1);
    float a[K0];
    {
        const float4* p = (const float4*)(in + (size_t)rr * K0);
        #pragma unroll
        for (int j = 0; j < K0 / 4; j++) {
            float4 v = p[j];
            a[4*j+0]=v.x; a[4*j+1]=v.y; a[4*j+2]=v.z; a[4*j+3]=v.w;
        }
    }
    float t1[HID];
    #pragma unroll 1
    for (int c4 = 0; c4 < HID/4; c4++) {
        float acc0 = b0[c4*4+0], acc1 = b0[c4*4+1], acc2 = b0[c4*4+2], acc3 = b0[c4*4+3];
        #pragma unroll
        for (int k = 0; k < K0; k++) {
            float av = a[k];
            acc0 = fmaf(av, w0t[(c4*4+0)*K0 + k], acc0);
            acc1 = fmaf(av, w0t[(c4*4+1)*K0 + k], acc1);
            acc2 = fmaf(av, w0t[(c4*4+2)*K0 + k], acc2);
            acc3 = fmaf(av, w0t[(c4*4+3)*K0 + k], acc3);
        }
        t1[c4*4+0] = fmaxf(acc0, 0.f);
        t1[c4*4+1] = fmaxf(acc1, 0.f);
        t1[c4*4+2] = fmaxf(acc2, 0.f);
        t1[c4*4+3] = fmaxf(acc3, 0.f);
    }
    float4* op = (float4*)(out + (size_t)rr * HID);
    const float4* hp = (const float4*)(RELU_RES ? (hprev + (size_t)rr * HID) : nullptr);
    #pragma unroll 1
    for (int c4 = 0; c4 < HID/4; c4++) {
        float acc0 = b1[c4*4+0], acc1 = b1[c4*4+1], acc2 = b1[c4*4+2], acc3 = b1[c4*4+3];
        #pragma unroll
        for (int k = 0; k < HID; k++) {
            float tv = t1[k];
            acc0 = fmaf(tv, w1t[(c4*4+0)*HID + k], acc0);
            acc1 = fmaf(tv, w1t[(c4*4+1)*HID + k], acc1);
            acc2 = fmaf(tv, w1t[(c4*4+2)*HID + k], acc2);
            acc3 = fmaf(tv, w1t[(c4*4+3)*HID + k], acc3);
        }
        float4 res;
        res.x = acc0; res.y = acc1; res.z = acc2; res.w = acc3;
        if (RELU_RES) {
            float4 h4 = hp[c4];
            res.x = fmaxf(res.x + h4.x, 0.f);
            res.y = fmaxf(res.y + h4.y, 0.f);
            res.z = fmaxf(res.z + h4.z, 0.f);
            res.w = fmaxf(res.w + h4.w, 0.f);
        }
        if (r < nrows) op[c4] = res;
    }
}

// ---------------- edge MLP2: natural-order compute, scatter rows to sorted slots --------
// e_sorted stored as bf16 pairs (uint32), row = 32 uints = 128 B.

__global__ __launch_bounds__(256) void k_edge_mlp(
    const float* __restrict__ eattr, const int* __restrict__ newpos,
    uint32* __restrict__ e_sorted,
    const float* __restrict__ w0t, const float* __restrict__ b0,
    const float* __restrict__ w1t, const float* __restrict__ b1)
{
    __shared__ uint32 tile[4][64 * 33];  // per-wave 64 rows x 32 packed words, +1 pad
    int wave = threadIdx.x >> 6, lane = threadIdx.x & 63;
    int gid = blockIdx.x * 256 + threadIdx.x;
    int eid = (gid < N_EDGES) ? gid : (N_EDGES - 1);

    float a[INE];
    {
        const float4* pr = (const float4*)(eattr + (size_t)eid * INE);
        #pragma unroll
        for (int j = 0; j < INE/4; j++) {
            float4 v = pr[j];
            a[4*j+0]=v.x; a[4*j+1]=v.y; a[4*j+2]=v.z; a[4*j+3]=v.w;
        }
    }
    float t1[HID];
    #pragma unroll 1
    for (int c4 = 0; c4 < HID/4; c4++) {
        float acc0 = b0[c4*4+0], acc1 = b0[c4*4+1], acc2 = b0[c4*4+2], acc3 = b0[c4*4+3];
        #pragma unroll
        for (int k = 0; k < INE; k++) {
            float av = a[k];
            acc0 = fmaf(av, w0t[(c4*4+0)*INE + k], acc0);
            acc1 = fmaf(av, w0t[(c4*4+1)*INE + k], acc1);
            acc2 = fmaf(av, w0t[(c4*4+2)*INE + k], acc2);
            acc3 = fmaf(av, w0t[(c4*4+3)*INE + k], acc3);
        }
        t1[c4*4+0] = fmaxf(acc0, 0.f);
        t1[c4*4+1] = fmaxf(acc1, 0.f);
        t1[c4*4+2] = fmaxf(acc2, 0.f);
        t1[c4*4+3] = fmaxf(acc3, 0.f);
    }
    uint32* my = &tile[wave][lane * 33];
    #pragma unroll 1
    for (int c4 = 0; c4 < HID/4; c4++) {
        float acc0 = b1[c4*4+0], acc1 = b1[c4*4+1], acc2 = b1[c4*4+2], acc3 = b1[c4*4+3];
        #pragma unroll
        for (int k = 0; k < HID; k++) {
            float tv = t1[k];
            acc0 = fmaf(tv, w1t[(c4*4+0)*HID + k], acc0);
            acc1 = fmaf(tv, w1t[(c4*4+1)*HID + k], acc1);
            acc2 = fmaf(tv, w1t[(c4*4+2)*HID + k], acc2);
            acc3 = fmaf(tv, w1t[(c4*4+3)*HID + k], acc3);
        }
        my[c4*2+0] = pack_bf2(acc0, acc1);
        my[c4*2+1] = pack_bf2(acc2, acc3);
    }
    __syncthreads();
    // scatter flush: each half-wave writes one 128 B row per iter (full cache lines)
    int half = lane >> 5, c = lane & 31;
    int waveBase = blockIdx.x * 256 + wave * 64;
    #pragma unroll 4
    for (int rr = 0; rr < 32; rr++) {
        int r2 = rr * 2 + half;
        int pos = waveBase + r2;
        if (pos < N_EDGES) {
            int drow = newpos[pos];
            e_sorted[(size_t)drow * 32 + c] = tile[wave][r2 * 33 + c];
        }
    }
}

// ------- GINE aggregation: z = sum relu(h[src]+e) + 1.1*h  (half-wave per edge) -------

__global__ __launch_bounds__(256) void k_agg(
    const float* __restrict__ h, const uint32* __restrict__ e_sorted,
    const int* __restrict__ rowptr, const int* __restrict__ perm_src,
    float* __restrict__ z)
{
    int node = blockIdx.x * 4 + (threadIdx.x >> 6);
    if (node >= N_NODES) return;
    int lane = threadIdx.x & 63;
    int half = lane >> 5, c = lane & 31;   // this lane covers channels 2c, 2c+1
    int r0 = rowptr[node], r1 = rowptr[node + 1];
    float accx = 0.f, accy = 0.f;
    int p = r0;
    for (; p + 8 <= r1; p += 8) {
        #pragma unroll
        for (int j = 0; j < 4; j++) {
            int idx = p + 2*j + half;
            int s = perm_src[idx];
            const float2 hv = *(const float2*)&h[(size_t)s * HID + 2*c];
            uint32 ev = e_sorted[(size_t)idx * 32 + c];
            accx += fmaxf(hv.x + bf_lo(ev), 0.f);
            accy += fmaxf(hv.y + bf_hi(ev), 0.f);
        }
    }
    for (; p < r1; p += 2) {
        int idx = p + half;
        if (idx < r1) {
            int s = perm_src[idx];
            const float2 hv = *(const float2*)&h[(size_t)s * HID + 2*c];
            uint32 ev = e_sorted[(size_t)idx * 32 + c];
            accx += fmaxf(hv.x + bf_lo(ev), 0.f);
            accy += fmaxf(hv.y + bf_hi(ev), 0.f);
        }
    }
    accx += __shfl_xor(accx, 32);
    accy += __shfl_xor(accy, 32);
    if (half == 0) {
        const float2 hn = *(const float2*)&h[(size_t)node * HID + 2*c];
        float2 res;
        res.x = fmaf(1.1f, hn.x, accx);
        res.y = fmaf(1.1f, hn.y, accy);
        *(float2*)&z[(size_t)node * HID + 2*c] = res;
    }
}

// ---------------- global add pool (batch is sorted) ----------------

__global__ __launch_bounds__(256) void k_pool(
    const float* __restrict__ h, const int* __restrict__ batch, float* __restrict__ out)
{
    int g = blockIdx.x;
    int lane = threadIdx.x & 63, wave = threadIdx.x >> 6;
    int lo = 0, hi = N_NODES;
    while (lo < hi) { int mid = (lo + hi) >> 1; if (batch[mid] < g) lo = mid + 1; else hi = mid; }
    int start = lo;
    hi = N_NODES;
    while (lo < hi) { int mid = (lo + hi) >> 1; if (batch[mid] < g + 1) lo = mid + 1; else hi = mid; }
    int end = lo;
    float acc = 0.f;
    for (int n = start + wave; n < end; n += 4)
        acc += h[(size_t)n*HID + lane];
    __shared__ float sh[4][64];
    sh[wave][lane] = acc;
    __syncthreads();
    if (wave == 0)
        out[(size_t)g*HID + lane] = sh[0][lane] + sh[1][lane] + sh[2][lane] + sh[3][lane];
}

// ---------------- launch ----------------

extern "C" void kernel_launch(void* const* d_in, const int* in_sizes, int n_in,
                              void* d_out, int out_size, void* d_ws, size_t ws_size,
                              hipStream_t stream) {
    const float* x     = (const float*)d_in[0];
    const int*   eidx  = (const int*)  d_in[1];
    const float* eattr = (const float*)d_in[2];
    const int*   batch = (const int*)  d_in[3];
    const float* wn0 = (const float*)d_in[4];  const float* bn0 = (const float*)d_in[5];
    const float* wn1 = (const float*)d_in[6];  const float* bn1 = (const float*)d_in[7];
    const float* we0 = (const float*)d_in[8];  const float* be0 = (const float*)d_in[9];
    const float* we1 = (const float*)d_in[10]; const float* be1 = (const float*)d_in[11];
    const float* cw0 = (const float*)d_in[12]; const float* cb0 = (const float*)d_in[13];
    const float* cw1 = (const float*)d_in[14]; const float* cb1 = (const float*)d_in[15];
    const float* lw0 = (const float*)d_in[16]; const float* lb0 = (const float*)d_in[17];
    const float* lw1 = (const float*)d_in[18]; const float* lb1 = (const float*)d_in[19];
    const int* src = eidx;
    const int* dst = eidx + N_EDGES;

    // workspace layout (~214 MB)
    char* ws = (char*)d_ws;
    size_t off = 0;
    auto alloc = [&](size_t bytes) -> void* {
        void* p = ws + off;
        off = (off + bytes + 255) & ~(size_t)255;
        return p;
    };
    int*   counts   = (int*)  alloc((size_t)N_NODES * 4);
    int*   rowptr   = (int*)  alloc((size_t)(N_NODES + 1) * 4);
    int*   cursor   = (int*)  alloc((size_t)N_NODES * 4);
    int*   bsums    = (int*)  alloc(128 * 4);
    int*   perm_src = (int*)  alloc((size_t)N_EDGES * 4);
    int*   newpos   = (int*)  alloc((size_t)N_EDGES * 4);
    float* wt       = (float*)alloc((size_t)44032 * 4);
    float* hA       = (float*)alloc((size_t)N_NODES * HID * 4);
    float* hB       = (float*)alloc((size_t)N_NODES * HID * 4);
    float* zbuf     = (float*)alloc((size_t)N_NODES * HID * 4);
    uint32* e_sorted = (uint32*)alloc((size_t)N_EDGES * HID * 2);
    if (off > ws_size) {
        k_diag<<<1, 64, 0, stream>>>((float*)d_out, 1.0e9f);
        return;
    }

    float* wn0t = wt + 0;
    float* wn1t = wt + 2048;
    float* we0t = wt + 6144;
    float* we1t = wt + 7168;
    float* cw0t = wt + 11264;
    float* cw1t = wt + 23552;
    float* lw0t = wt + 35840;
    float* lw1t = wt + 39936;

    const int NB = (N_NODES + 1023) / 1024;  // 98

    hipMemsetAsync(counts, 0, (size_t)N_NODES * 4, stream);
    k_hist<<<(N_EDGES + 255) / 256, 256, 0, stream>>>(dst, counts);
    k_scan1<<<NB, 256, 0, stream>>>(counts, bsums);
    k_scan2<<<1, 128, 0, stream>>>(bsums, NB);
    k_scan3<<<NB, 256, 0, stream>>>(counts, bsums, rowptr, cursor);
    k_fill<<<(N_EDGES + 255) / 256, 256, 0, stream>>>(src, dst, cursor, perm_src, newpos);

    TransJobs jobs;
    jobs.j[0]  = { wn0, wn0t, INN, HID };
    jobs.j[1]  = { wn1, wn1t, HID, HID };
    jobs.j[2]  = { we0, we0t, INE, HID };
    jobs.j[3]  = { we1, we1t, HID, HID };
    for (int l = 0; l < 3; l++) {
        jobs.j[4 + l] = { cw0 + l * 4096, cw0t + l * 4096, HID, HID };
        jobs.j[7 + l] = { cw1 + l * 4096, cw1t + l * 4096, HID, HID };
    }
    jobs.j[10] = { lw0, lw0t, HID, HID };
    jobs.j[11] = { lw1, lw1t, HID, HID };
    k_transpose_all<<<12, 256, 0, stream>>>(jobs);

    const int NGRID = (N_NODES + 255) / 256;  // 391

    k_mlp<INN, false><<<NGRID, 256, 0, stream>>>(x, nullptr, hA, wn0t, bn0, wn1t, bn1, N_NODES);

    k_edge_mlp<<<(N_EDGES + 255) / 256, 256, 0, stream>>>(eattr, newpos, e_sorted,
                                                          we0t, be0, we1t, be1);

    float* hcur = hA;
    float* hnxt = hB;
    const int AGRID = (N_NODES + 3) / 4;  // 25000
    for (int l = 0; l < 3; l++) {
        k_agg<<<AGRID, 256, 0, stream>>>(hcur, e_sorted, rowptr, perm_src, zbuf);
        k_mlp<HID, true><<<NGRID, 256, 0, stream>>>(zbuf, hcur, hnxt,
                                                    cw0t + l * 4096, cb0 + l * 64,
                                                    cw1t + l * 4096, cb1 + l * 64, N_NODES);
        float* t = hcur; hcur = hnxt; hnxt = t;
    }
    k_agg<<<AGRID, 256, 0, stream>>>(hcur, e_sorted, rowptr, perm_src, zbuf);
    k_mlp<HID, false><<<NGRID, 256, 0, stream>>>(zbuf, nullptr, hnxt,
                                                 lw0t, lb0, lw1t, lb1, N_NODES);

    k_pool<<<N_GRAPHS, 256, 0, stream>>>(hnxt, batch, (float*)d_out);
}

// Round 4
// 1261.218 us; speedup vs baseline: 1.1694x; 1.0774x over previous
//
#include <hip/hip_runtime.h>
#include <hip/hip_bf16.h>
#include <stdint.h>

#define N_NODES 100000
#define N_EDGES 1000000
#define N_GRAPHS 512
#define HID 64
#define INN 32
#define INE 16

typedef unsigned int uint32;
typedef unsigned short ushort16;

__device__ __forceinline__ ushort16 f2bf(float f) {
    uint32 u = __float_as_uint(f);
    uint32 r = (u + 0x7fffu + ((u >> 16) & 1u)) >> 16;  // RNE
    return (ushort16)r;
}
__device__ __forceinline__ uint32 pack_bf2(float lo, float hi) {
    return (uint32)f2bf(lo) | ((uint32)f2bf(hi) << 16);
}
__device__ __forceinline__ float bf_lo(uint32 v) { return __uint_as_float(v << 16); }
__device__ __forceinline__ float bf_hi(uint32 v) { return __uint_as_float(v & 0xffff0000u); }

// ---------------- diag ----------------

__global__ void k_diag(float* out, float val) { out[threadIdx.x] = val; }

// ---------------- CSR build ----------------

__global__ void k_hist(const int* __restrict__ dst, int* __restrict__ counts) {
    int e = blockIdx.x * 256 + threadIdx.x;
    if (e < N_EDGES) atomicAdd(&counts[dst[e]], 1);
}

__global__ void k_scan1(const int* __restrict__ counts, int* __restrict__ bsums) {
    __shared__ int sdata[256];
    int b = blockIdx.x;
    int s = 0;
    for (int j = threadIdx.x; j < 1024; j += 256) {
        int i = b * 1024 + j;
        s += (i < N_NODES) ? counts[i] : 0;
    }
    sdata[threadIdx.x] = s; __syncthreads();
    for (int off = 128; off > 0; off >>= 1) {
        if (threadIdx.x < off) sdata[threadIdx.x] += sdata[threadIdx.x + off];
        __syncthreads();
    }
    if (threadIdx.x == 0) bsums[b] = sdata[0];
}

__global__ void k_scan2(int* __restrict__ bsums, int nb) {
    __shared__ int sh[128];
    int v = (threadIdx.x < nb) ? bsums[threadIdx.x] : 0;
    sh[threadIdx.x] = v; __syncthreads();
    for (int off = 1; off < 128; off <<= 1) {
        int t = (threadIdx.x >= off) ? sh[threadIdx.x - off] : 0;
        __syncthreads();
        sh[threadIdx.x] += t;
        __syncthreads();
    }
    if (threadIdx.x < nb) bsums[threadIdx.x] = sh[threadIdx.x] - v;  // exclusive
}

__global__ void k_scan3(const int* __restrict__ counts, const int* __restrict__ bsums,
                        int* __restrict__ rowptr, int* __restrict__ cursor) {
    __shared__ int sh[256];
    int b = blockIdx.x;
    int base = b * 1024;
    int v[4]; int s = 0;
    #pragma unroll
    for (int j = 0; j < 4; j++) {
        int i = base + threadIdx.x * 4 + j;
        v[j] = (i < N_NODES) ? counts[i] : 0;
        s += v[j];
    }
    sh[threadIdx.x] = s; __syncthreads();
    for (int off = 1; off < 256; off <<= 1) {
        int t = (threadIdx.x >= off) ? sh[threadIdx.x - off] : 0;
        __syncthreads();
        sh[threadIdx.x] += t;
        __syncthreads();
    }
    int excl = sh[threadIdx.x] - s + bsums[b];
    #pragma unroll
    for (int j = 0; j < 4; j++) {
        int i = base + threadIdx.x * 4 + j;
        if (i < N_NODES) { rowptr[i] = excl; cursor[i] = excl; excl += v[j]; }
    }
    if (b == gridDim.x - 1 && threadIdx.x == 255) rowptr[N_NODES] = excl;
}

// newpos[e] = slot of edge e in the dst-sorted order (inverse permutation)
__global__ void k_fill(const int* __restrict__ src, const int* __restrict__ dst,
                       int* __restrict__ cursor, int* __restrict__ perm_src,
                       int* __restrict__ newpos) {
    int e = blockIdx.x * 256 + threadIdx.x;
    if (e < N_EDGES) {
        int d = dst[e];
        int p = atomicAdd(&cursor[d], 1);
        perm_src[p] = src[e];
        newpos[e] = p;
    }
}

// ---------------- weight transposes ----------------

struct TransJob { const float* w; float* wt; int K; int C; };
struct TransJobs { TransJob j[12]; };

__global__ void k_transpose_all(TransJobs jobs) {
    TransJob t = jobs.j[blockIdx.x];
    int n = t.K * t.C;
    for (int i = threadIdx.x; i < n; i += 256) {
        int k = i / t.C, c = i % t.C;
        t.wt[c * t.K + k] = t.w[i];
    }
}

// ---------------- node-side MLP2 (lane = row) ----------------
// __launch_bounds__(256,2): VGPR cap 256 so a[64]+t1[64] stay in registers (no scratch spill)

template<int K0, bool RELU_RES>
__global__ __launch_bounds__(256, 2) void k_mlp(
    const float* __restrict__ in, const float* __restrict__ hprev, float* __restrict__ out,
    const float* __restrict__ w0t, const float* __restrict__ b0,
    const float* __restrict__ w1t, const float* __restrict__ b1, int nrows)
{
    int r = blockIdx.x * 256 + threadIdx.x;
    int rr = (r < nrows) ? r : (nrows - 1);
    float a[K0];
    {
        const float4* p = (const float4*)(in + (size_t)rr * K0);
        #pragma unroll
        for (int j = 0; j < K0 / 4; j++) {
            float4 v = p[j];
            a[4*j+0]=v.x; a[4*j+1]=v.y; a[4*j+2]=v.z; a[4*j+3]=v.w;
        }
    }
    float t1[HID];
    #pragma unroll 1
    for (int c4 = 0; c4 < HID/4; c4++) {
        float acc0 = b0[c4*4+0], acc1 = b0[c4*4+1], acc2 = b0[c4*4+2], acc3 = b0[c4*4+3];
        #pragma unroll
        for (int k = 0; k < K0; k++) {
            float av = a[k];
            acc0 = fmaf(av, w0t[(c4*4+0)*K0 + k], acc0);
            acc1 = fmaf(av, w0t[(c4*4+1)*K0 + k], acc1);
            acc2 = fmaf(av, w0t[(c4*4+2)*K0 + k], acc2);
            acc3 = fmaf(av, w0t[(c4*4+3)*K0 + k], acc3);
        }
        t1[c4*4+0] = fmaxf(acc0, 0.f);
        t1[c4*4+1] = fmaxf(acc1, 0.f);
        t1[c4*4+2] = fmaxf(acc2, 0.f);
        t1[c4*4+3] = fmaxf(acc3, 0.f);
    }
    float4* op = (float4*)(out + (size_t)rr * HID);
    const float4* hp = (const float4*)(RELU_RES ? (hprev + (size_t)rr * HID) : nullptr);
    #pragma unroll 1
    for (int c4 = 0; c4 < HID/4; c4++) {
        float acc0 = b1[c4*4+0], acc1 = b1[c4*4+1], acc2 = b1[c4*4+2], acc3 = b1[c4*4+3];
        #pragma unroll
        for (int k = 0; k < HID; k++) {
            float tv = t1[k];
            acc0 = fmaf(tv, w1t[(c4*4+0)*HID + k], acc0);
            acc1 = fmaf(tv, w1t[(c4*4+1)*HID + k], acc1);
            acc2 = fmaf(tv, w1t[(c4*4+2)*HID + k], acc2);
            acc3 = fmaf(tv, w1t[(c4*4+3)*HID + k], acc3);
        }
        float4 res;
        res.x = acc0; res.y = acc1; res.z = acc2; res.w = acc3;
        if (RELU_RES) {
            float4 h4 = hp[c4];
            res.x = fmaxf(res.x + h4.x, 0.f);
            res.y = fmaxf(res.y + h4.y, 0.f);
            res.z = fmaxf(res.z + h4.z, 0.f);
            res.w = fmaxf(res.w + h4.w, 0.f);
        }
        if (r < nrows) op[c4] = res;
    }
}

// ---------------- edge MLP2: natural-order compute, scatter rows to sorted slots --------
// e_sorted stored as bf16 pairs (uint32), row = 32 uints = 128 B.
// __launch_bounds__(256,3): VGPR cap ~170 so t1[64] stays in registers (no scratch spill)

__global__ __launch_bounds__(256, 3) void k_edge_mlp(
    const float* __restrict__ eattr, const int* __restrict__ newpos,
    uint32* __restrict__ e_sorted,
    const float* __restrict__ w0t, const float* __restrict__ b0,
    const float* __restrict__ w1t, const float* __restrict__ b1)
{
    __shared__ uint32 tile[4][64 * 33];  // per-wave 64 rows x 32 packed words, +1 pad
    int wave = threadIdx.x >> 6, lane = threadIdx.x & 63;
    int gid = blockIdx.x * 256 + threadIdx.x;
    int eid = (gid < N_EDGES) ? gid : (N_EDGES - 1);

    float a[INE];
    {
        const float4* pr = (const float4*)(eattr + (size_t)eid * INE);
        #pragma unroll
        for (int j = 0; j < INE/4; j++) {
            float4 v = pr[j];
            a[4*j+0]=v.x; a[4*j+1]=v.y; a[4*j+2]=v.z; a[4*j+3]=v.w;
        }
    }
    float t1[HID];
    #pragma unroll 1
    for (int c4 = 0; c4 < HID/4; c4++) {
        float acc0 = b0[c4*4+0], acc1 = b0[c4*4+1], acc2 = b0[c4*4+2], acc3 = b0[c4*4+3];
        #pragma unroll
        for (int k = 0; k < INE; k++) {
            float av = a[k];
            acc0 = fmaf(av, w0t[(c4*4+0)*INE + k], acc0);
            acc1 = fmaf(av, w0t[(c4*4+1)*INE + k], acc1);
            acc2 = fmaf(av, w0t[(c4*4+2)*INE + k], acc2);
            acc3 = fmaf(av, w0t[(c4*4+3)*INE + k], acc3);
        }
        t1[c4*4+0] = fmaxf(acc0, 0.f);
        t1[c4*4+1] = fmaxf(acc1, 0.f);
        t1[c4*4+2] = fmaxf(acc2, 0.f);
        t1[c4*4+3] = fmaxf(acc3, 0.f);
    }
    uint32* my = &tile[wave][lane * 33];
    #pragma unroll 1
    for (int c4 = 0; c4 < HID/4; c4++) {
        float acc0 = b1[c4*4+0], acc1 = b1[c4*4+1], acc2 = b1[c4*4+2], acc3 = b1[c4*4+3];
        #pragma unroll
        for (int k = 0; k < HID; k++) {
            float tv = t1[k];
            acc0 = fmaf(tv, w1t[(c4*4+0)*HID + k], acc0);
            acc1 = fmaf(tv, w1t[(c4*4+1)*HID + k], acc1);
            acc2 = fmaf(tv, w1t[(c4*4+2)*HID + k], acc2);
            acc3 = fmaf(tv, w1t[(c4*4+3)*HID + k], acc3);
        }
        my[c4*2+0] = pack_bf2(acc0, acc1);
        my[c4*2+1] = pack_bf2(acc2, acc3);
    }
    __syncthreads();
    // scatter flush: each half-wave writes one 128 B row per iter (full cache lines)
    int half = lane >> 5, c = lane & 31;
    int waveBase = blockIdx.x * 256 + wave * 64;
    #pragma unroll 4
    for (int rr = 0; rr < 32; rr++) {
        int r2 = rr * 2 + half;
        int pos = waveBase + r2;
        if (pos < N_EDGES) {
            int drow = newpos[pos];
            e_sorted[(size_t)drow * 32 + c] = tile[wave][r2 * 33 + c];
        }
    }
}

// ------- GINE aggregation: z = sum relu(h[src]+e) + 1.1*h  (half-wave per edge) -------

__global__ __launch_bounds__(256) void k_agg(
    const float* __restrict__ h, const uint32* __restrict__ e_sorted,
    const int* __restrict__ rowptr, const int* __restrict__ perm_src,
    float* __restrict__ z)
{
    int node = blockIdx.x * 4 + (threadIdx.x >> 6);
    if (node >= N_NODES) return;
    int lane = threadIdx.x & 63;
    int half = lane >> 5, c = lane & 31;   // this lane covers channels 2c, 2c+1
    int r0 = rowptr[node], r1 = rowptr[node + 1];
    float accx = 0.f, accy = 0.f;
    int p = r0;
    for (; p + 8 <= r1; p += 8) {
        #pragma unroll
        for (int j = 0; j < 4; j++) {
            int idx = p + 2*j + half;
            int s = perm_src[idx];
            const float2 hv = *(const float2*)&h[(size_t)s * HID + 2*c];
            uint32 ev = e_sorted[(size_t)idx * 32 + c];
            accx += fmaxf(hv.x + bf_lo(ev), 0.f);
            accy += fmaxf(hv.y + bf_hi(ev), 0.f);
        }
    }
    for (; p < r1; p += 2) {
        int idx = p + half;
        if (idx < r1) {
            int s = perm_src[idx];
            const float2 hv = *(const float2*)&h[(size_t)s * HID + 2*c];
            uint32 ev = e_sorted[(size_t)idx * 32 + c];
            accx += fmaxf(hv.x + bf_lo(ev), 0.f);
            accy += fmaxf(hv.y + bf_hi(ev), 0.f);
        }
    }
    accx += __shfl_xor(accx, 32);
    accy += __shfl_xor(accy, 32);
    if (half == 0) {
        const float2 hn = *(const float2*)&h[(size_t)node * HID + 2*c];
        float2 res;
        res.x = fmaf(1.1f, hn.x, accx);
        res.y = fmaf(1.1f, hn.y, accy);
        *(float2*)&z[(size_t)node * HID + 2*c] = res;
    }
}

// ---------------- global add pool (batch is sorted) ----------------

__global__ __launch_bounds__(256) void k_pool(
    const float* __restrict__ h, const int* __restrict__ batch, float* __restrict__ out)
{
    int g = blockIdx.x;
    int lane = threadIdx.x & 63, wave = threadIdx.x >> 6;
    int lo = 0, hi = N_NODES;
    while (lo < hi) { int mid = (lo + hi) >> 1; if (batch[mid] < g) lo = mid + 1; else hi = mid; }
    int start = lo;
    hi = N_NODES;
    while (lo < hi) { int mid = (lo + hi) >> 1; if (batch[mid] < g + 1) lo = mid + 1; else hi = mid; }
    int end = lo;
    float acc = 0.f;
    for (int n = start + wave; n < end; n += 4)
        acc += h[(size_t)n*HID + lane];
    __shared__ float sh[4][64];
    sh[wave][lane] = acc;
    __syncthreads();
    if (wave == 0)
        out[(size_t)g*HID + lane] = sh[0][lane] + sh[1][lane] + sh[2][lane] + sh[3][lane];
}

// ---------------- launch ----------------

extern "C" void kernel_launch(void* const* d_in, const int* in_sizes, int n_in,
                              void* d_out, int out_size, void* d_ws, size_t ws_size,
                              hipStream_t stream) {
    const float* x     = (const float*)d_in[0];
    const int*   eidx  = (const int*)  d_in[1];
    const float* eattr = (const float*)d_in[2];
    const int*   batch = (const int*)  d_in[3];
    const float* wn0 = (const float*)d_in[4];  const float* bn0 = (const float*)d_in[5];
    const float* wn1 = (const float*)d_in[6];  const float* bn1 = (const float*)d_in[7];
    const float* we0 = (const float*)d_in[8];  const float* be0 = (const float*)d_in[9];
    const float* we1 = (const float*)d_in[10]; const float* be1 = (const float*)d_in[11];
    const float* cw0 = (const float*)d_in[12]; const float* cb0 = (const float*)d_in[13];
    const float* cw1 = (const float*)d_in[14]; const float* cb1 = (const float*)d_in[15];
    const float* lw0 = (const float*)d_in[16]; const float* lb0 = (const float*)d_in[17];
    const float* lw1 = (const float*)d_in[18]; const float* lb1 = (const float*)d_in[19];
    const int* src = eidx;
    const int* dst = eidx + N_EDGES;

    // workspace layout (~214 MB)
    char* ws = (char*)d_ws;
    size_t off = 0;
    auto alloc = [&](size_t bytes) -> void* {
        void* p = ws + off;
        off = (off + bytes + 255) & ~(size_t)255;
        return p;
    };
    int*   counts   = (int*)  alloc((size_t)N_NODES * 4);
    int*   rowptr   = (int*)  alloc((size_t)(N_NODES + 1) * 4);
    int*   cursor   = (int*)  alloc((size_t)N_NODES * 4);
    int*   bsums    = (int*)  alloc(128 * 4);
    int*   perm_src = (int*)  alloc((size_t)N_EDGES * 4);
    int*   newpos   = (int*)  alloc((size_t)N_EDGES * 4);
    float* wt       = (float*)alloc((size_t)44032 * 4);
    float* hA       = (float*)alloc((size_t)N_NODES * HID * 4);
    float* hB       = (float*)alloc((size_t)N_NODES * HID * 4);
    float* zbuf     = (float*)alloc((size_t)N_NODES * HID * 4);
    uint32* e_sorted = (uint32*)alloc((size_t)N_EDGES * HID * 2);
    if (off > ws_size) {
        k_diag<<<1, 64, 0, stream>>>((float*)d_out, 1.0e9f);
        return;
    }

    float* wn0t = wt + 0;
    float* wn1t = wt + 2048;
    float* we0t = wt + 6144;
    float* we1t = wt + 7168;
    float* cw0t = wt + 11264;
    float* cw1t = wt + 23552;
    float* lw0t = wt + 35840;
    float* lw1t = wt + 39936;

    const int NB = (N_NODES + 1023) / 1024;  // 98

    hipMemsetAsync(counts, 0, (size_t)N_NODES * 4, stream);
    k_hist<<<(N_EDGES + 255) / 256, 256, 0, stream>>>(dst, counts);
    k_scan1<<<NB, 256, 0, stream>>>(counts, bsums);
    k_scan2<<<1, 128, 0, stream>>>(bsums, NB);
    k_scan3<<<NB, 256, 0, stream>>>(counts, bsums, rowptr, cursor);
    k_fill<<<(N_EDGES + 255) / 256, 256, 0, stream>>>(src, dst, cursor, perm_src, newpos);

    TransJobs jobs;
    jobs.j[0]  = { wn0, wn0t, INN, HID };
    jobs.j[1]  = { wn1, wn1t, HID, HID };
    jobs.j[2]  = { we0, we0t, INE, HID };
    jobs.j[3]  = { we1, we1t, HID, HID };
    for (int l = 0; l < 3; l++) {
        jobs.j[4 + l] = { cw0 + l * 4096, cw0t + l * 4096, HID, HID };
        jobs.j[7 + l] = { cw1 + l * 4096, cw1t + l * 4096, HID, HID };
    }
    jobs.j[10] = { lw0, lw0t, HID, HID };
    jobs.j[11] = { lw1, lw1t, HID, HID };
    k_transpose_all<<<12, 256, 0, stream>>>(jobs);

    const int NGRID = (N_NODES + 255) / 256;  // 391

    k_mlp<INN, false><<<NGRID, 256, 0, stream>>>(x, nullptr, hA, wn0t, bn0, wn1t, bn1, N_NODES);

    k_edge_mlp<<<(N_EDGES + 255) / 256, 256, 0, stream>>>(eattr, newpos, e_sorted,
                                                          we0t, be0, we1t, be1);

    float* hcur = hA;
    float* hnxt = hB;
    const int AGRID = (N_NODES + 3) / 4;  // 25000
    for (int l = 0; l < 3; l++) {
        k_agg<<<AGRID, 256, 0, stream>>>(hcur, e_sorted, rowptr, perm_src, zbuf);
        k_mlp<HID, true><<<NGRID, 256, 0, stream>>>(zbuf, hcur, hnxt,
                                                    cw0t + l * 4096, cb0 + l * 64,
                                                    cw1t + l * 4096, cb1 + l * 64, N_NODES);
        float* t = hcur; hcur = hnxt; hnxt = t;
    }
    k_agg<<<AGRID, 256, 0, stream>>>(hcur, e_sorted, rowptr, perm_src, zbuf);
    k_mlp<HID, false><<<NGRID, 256, 0, stream>>>(zbuf, nullptr, hnxt,
                                                 lw0t, lb0, lw1t, lb1, N_NODES);

    k_pool<<<N_GRAPHS, 256, 0, stream>>>(hnxt, batch, (float*)d_out);
}

// Round 5
// 1082.873 us; speedup vs baseline: 1.3621x; 1.1647x over previous
//
#include <hip/hip_runtime.h>
#include <hip/hip_bf16.h>
#include <stdint.h>

#define N_NODES 100000
#define N_EDGES 1000000
#define N_GRAPHS 512
#define HID 64
#define INN 32
#define INE 16

typedef unsigned int uint32;
typedef unsigned short ushort16;

__device__ __forceinline__ ushort16 f2bf(float f) {
    uint32 u = __float_as_uint(f);
    uint32 r = (u + 0x7fffu + ((u >> 16) & 1u)) >> 16;  // RNE
    return (ushort16)r;
}
__device__ __forceinline__ uint32 pack_bf2(float lo, float hi) {
    return (uint32)f2bf(lo) | ((uint32)f2bf(hi) << 16);
}
__device__ __forceinline__ float bf_lo(uint32 v) { return __uint_as_float(v << 16); }
__device__ __forceinline__ float bf_hi(uint32 v) { return __uint_as_float(v & 0xffff0000u); }

// ---------------- diag ----------------

__global__ void k_diag(float* out, float val) { out[threadIdx.x] = val; }

// ---------------- CSR build ----------------

__global__ void k_hist(const int* __restrict__ dst, int* __restrict__ counts) {
    int e = blockIdx.x * 256 + threadIdx.x;
    if (e < N_EDGES) atomicAdd(&counts[dst[e]], 1);
}

__global__ void k_scan1(const int* __restrict__ counts, int* __restrict__ bsums) {
    __shared__ int sdata[256];
    int b = blockIdx.x;
    int s = 0;
    for (int j = threadIdx.x; j < 1024; j += 256) {
        int i = b * 1024 + j;
        s += (i < N_NODES) ? counts[i] : 0;
    }
    sdata[threadIdx.x] = s; __syncthreads();
    for (int off = 128; off > 0; off >>= 1) {
        if (threadIdx.x < off) sdata[threadIdx.x] += sdata[threadIdx.x + off];
        __syncthreads();
    }
    if (threadIdx.x == 0) bsums[b] = sdata[0];
}

__global__ void k_scan2(int* __restrict__ bsums, int nb) {
    __shared__ int sh[128];
    int v = (threadIdx.x < nb) ? bsums[threadIdx.x] : 0;
    sh[threadIdx.x] = v; __syncthreads();
    for (int off = 1; off < 128; off <<= 1) {
        int t = (threadIdx.x >= off) ? sh[threadIdx.x - off] : 0;
        __syncthreads();
        sh[threadIdx.x] += t;
        __syncthreads();
    }
    if (threadIdx.x < nb) bsums[threadIdx.x] = sh[threadIdx.x] - v;  // exclusive
}

__global__ void k_scan3(const int* __restrict__ counts, const int* __restrict__ bsums,
                        int* __restrict__ rowptr, int* __restrict__ cursor) {
    __shared__ int sh[256];
    int b = blockIdx.x;
    int base = b * 1024;
    int v[4]; int s = 0;
    #pragma unroll
    for (int j = 0; j < 4; j++) {
        int i = base + threadIdx.x * 4 + j;
        v[j] = (i < N_NODES) ? counts[i] : 0;
        s += v[j];
    }
    sh[threadIdx.x] = s; __syncthreads();
    for (int off = 1; off < 256; off <<= 1) {
        int t = (threadIdx.x >= off) ? sh[threadIdx.x - off] : 0;
        __syncthreads();
        sh[threadIdx.x] += t;
        __syncthreads();
    }
    int excl = sh[threadIdx.x] - s + bsums[b];
    #pragma unroll
    for (int j = 0; j < 4; j++) {
        int i = base + threadIdx.x * 4 + j;
        if (i < N_NODES) { rowptr[i] = excl; cursor[i] = excl; excl += v[j]; }
    }
    if (b == gridDim.x - 1 && threadIdx.x == 255) rowptr[N_NODES] = excl;
}

// newpos[e] = slot of edge e in the dst-sorted order (inverse permutation)
__global__ void k_fill(const int* __restrict__ src, const int* __restrict__ dst,
                       int* __restrict__ cursor, int* __restrict__ perm_src,
                       int* __restrict__ newpos) {
    int e = blockIdx.x * 256 + threadIdx.x;
    if (e < N_EDGES) {
        int d = dst[e];
        int p = atomicAdd(&cursor[d], 1);
        perm_src[p] = src[e];
        newpos[e] = p;
    }
}

// ---------------- weight transposes (w0-type only; w1-type used naturally) ----------------

struct TransJob { const float* w; float* wt; int K; int C; };
struct TransJobs { TransJob j[6]; };

__global__ void k_transpose_all(TransJobs jobs) {
    TransJob t = jobs.j[blockIdx.x];
    int n = t.K * t.C;
    for (int i = threadIdx.x; i < n; i += 256) {
        int k = i / t.C, c = i % t.C;
        t.wt[c * t.K + k] = t.w[i];
    }
}

// ---------------- fused node-side MLP2 (lane = row, no t1 array) ----------------
// acc[c] = b1[c] + sum_k relu(b0[k] + sum_m a[m] w0[m][k]) * w1[k][c]
// All register arrays constant-indexed (fully unrolled) -> no scratch.

template<int K0, bool RELU_RES>
__global__ __launch_bounds__(256, 2) void k_mlp(
    const float* __restrict__ in, const float* __restrict__ hprev, float* __restrict__ out,
    const float* __restrict__ w0t, const float* __restrict__ b0,
    const float* __restrict__ w1, const float* __restrict__ b1, int nrows)
{
    int r = blockIdx.x * 256 + threadIdx.x;
    int rr = (r < nrows) ? r : (nrows - 1);
    float a[K0];
    {
        const float4* p = (const float4*)(in + (size_t)rr * K0);
        #pragma unroll
        for (int j = 0; j < K0 / 4; j++) {
            float4 v = p[j];
            a[4*j+0]=v.x; a[4*j+1]=v.y; a[4*j+2]=v.z; a[4*j+3]=v.w;
        }
    }
    float acc[HID];
    #pragma unroll
    for (int c = 0; c < HID; c++) acc[c] = b1[c];

    #pragma unroll 1
    for (int kk = 0; kk < HID / 4; kk++) {
        float t0 = b0[kk*4+0], t1v = b0[kk*4+1], t2 = b0[kk*4+2], t3 = b0[kk*4+3];
        #pragma unroll
        for (int m = 0; m < K0; m++) {
            float av = a[m];
            t0  = fmaf(av, w0t[(kk*4+0)*K0 + m], t0);
            t1v = fmaf(av, w0t[(kk*4+1)*K0 + m], t1v);
            t2  = fmaf(av, w0t[(kk*4+2)*K0 + m], t2);
            t3  = fmaf(av, w0t[(kk*4+3)*K0 + m], t3);
        }
        t0 = fmaxf(t0, 0.f); t1v = fmaxf(t1v, 0.f);
        t2 = fmaxf(t2, 0.f); t3 = fmaxf(t3, 0.f);
        const float* w1r0 = w1 + (kk*4+0) * HID;
        const float* w1r1 = w1 + (kk*4+1) * HID;
        const float* w1r2 = w1 + (kk*4+2) * HID;
        const float* w1r3 = w1 + (kk*4+3) * HID;
        #pragma unroll
        for (int c = 0; c < HID; c++) {
            float v = acc[c];
            v = fmaf(t0,  w1r0[c], v);
            v = fmaf(t1v, w1r1[c], v);
            v = fmaf(t2,  w1r2[c], v);
            v = fmaf(t3,  w1r3[c], v);
            acc[c] = v;
        }
    }

    float4* op = (float4*)(out + (size_t)rr * HID);
    const float4* hp = (const float4*)(RELU_RES ? (hprev + (size_t)rr * HID) : nullptr);
    #pragma unroll
    for (int c4 = 0; c4 < HID/4; c4++) {
        float4 res;
        res.x = acc[c4*4+0]; res.y = acc[c4*4+1];
        res.z = acc[c4*4+2]; res.w = acc[c4*4+3];
        if (RELU_RES) {
            float4 h4 = hp[c4];
            res.x = fmaxf(res.x + h4.x, 0.f);
            res.y = fmaxf(res.y + h4.y, 0.f);
            res.z = fmaxf(res.z + h4.z, 0.f);
            res.w = fmaxf(res.w + h4.w, 0.f);
        }
        if (r < nrows) op[c4] = res;
    }
}

// ---------------- fused edge MLP2: natural order, scatter rows to sorted slots --------
// e_sorted stored as bf16 pairs (uint32), row = 32 uints = 128 B.

__global__ __launch_bounds__(256, 3) void k_edge_mlp(
    const float* __restrict__ eattr, const int* __restrict__ newpos,
    uint32* __restrict__ e_sorted,
    const float* __restrict__ w0t, const float* __restrict__ b0,
    const float* __restrict__ w1, const float* __restrict__ b1)
{
    __shared__ uint32 tile[4][64 * 33];  // per-wave 64 rows x 32 packed words, +1 pad
    int wave = threadIdx.x >> 6, lane = threadIdx.x & 63;
    int gid = blockIdx.x * 256 + threadIdx.x;
    int eid = (gid < N_EDGES) ? gid : (N_EDGES - 1);

    float a[INE];
    {
        const float4* pr = (const float4*)(eattr + (size_t)eid * INE);
        #pragma unroll
        for (int j = 0; j < INE/4; j++) {
            float4 v = pr[j];
            a[4*j+0]=v.x; a[4*j+1]=v.y; a[4*j+2]=v.z; a[4*j+3]=v.w;
        }
    }
    float acc[HID];
    #pragma unroll
    for (int c = 0; c < HID; c++) acc[c] = b1[c];

    #pragma unroll 1
    for (int kk = 0; kk < HID / 4; kk++) {
        float t0 = b0[kk*4+0], t1v = b0[kk*4+1], t2 = b0[kk*4+2], t3 = b0[kk*4+3];
        #pragma unroll
        for (int m = 0; m < INE; m++) {
            float av = a[m];
            t0  = fmaf(av, w0t[(kk*4+0)*INE + m], t0);
            t1v = fmaf(av, w0t[(kk*4+1)*INE + m], t1v);
            t2  = fmaf(av, w0t[(kk*4+2)*INE + m], t2);
            t3  = fmaf(av, w0t[(kk*4+3)*INE + m], t3);
        }
        t0 = fmaxf(t0, 0.f); t1v = fmaxf(t1v, 0.f);
        t2 = fmaxf(t2, 0.f); t3 = fmaxf(t3, 0.f);
        const float* w1r0 = w1 + (kk*4+0) * HID;
        const float* w1r1 = w1 + (kk*4+1) * HID;
        const float* w1r2 = w1 + (kk*4+2) * HID;
        const float* w1r3 = w1 + (kk*4+3) * HID;
        #pragma unroll
        for (int c = 0; c < HID; c++) {
            float v = acc[c];
            v = fmaf(t0,  w1r0[c], v);
            v = fmaf(t1v, w1r1[c], v);
            v = fmaf(t2,  w1r2[c], v);
            v = fmaf(t3,  w1r3[c], v);
            acc[c] = v;
        }
    }

    uint32* my = &tile[wave][lane * 33];
    #pragma unroll
    for (int c2 = 0; c2 < 32; c2++)
        my[c2] = pack_bf2(acc[2*c2], acc[2*c2+1]);
    __syncthreads();
    // scatter flush: each half-wave writes one 128 B row per iter (full cache lines)
    int half = lane >> 5, c = lane & 31;
    int waveBase = blockIdx.x * 256 + wave * 64;
    #pragma unroll 4
    for (int rr = 0; rr < 32; rr++) {
        int r2 = rr * 2 + half;
        int pos = waveBase + r2;
        if (pos < N_EDGES) {
            int drow = newpos[pos];
            e_sorted[(size_t)drow * 32 + c] = tile[wave][r2 * 33 + c];
        }
    }
}

// ------- GINE aggregation: z = sum relu(h[src]+e) + 1.1*h  (half-wave per edge) -------

__global__ __launch_bounds__(256) void k_agg(
    const float* __restrict__ h, const uint32* __restrict__ e_sorted,
    const int* __restrict__ rowptr, const int* __restrict__ perm_src,
    float* __restrict__ z)
{
    int node = blockIdx.x * 4 + (threadIdx.x >> 6);
    if (node >= N_NODES) return;
    int lane = threadIdx.x & 63;
    int half = lane >> 5, c = lane & 31;   // this lane covers channels 2c, 2c+1
    int r0 = rowptr[node], r1 = rowptr[node + 1];
    float accx = 0.f, accy = 0.f;
    int p = r0;
    for (; p + 8 <= r1; p += 8) {
        #pragma unroll
        for (int j = 0; j < 4; j++) {
            int idx = p + 2*j + half;
            int s = perm_src[idx];
            const float2 hv = *(const float2*)&h[(size_t)s * HID + 2*c];
            uint32 ev = e_sorted[(size_t)idx * 32 + c];
            accx += fmaxf(hv.x + bf_lo(ev), 0.f);
            accy += fmaxf(hv.y + bf_hi(ev), 0.f);
        }
    }
    for (; p < r1; p += 2) {
        int idx = p + half;
        if (idx < r1) {
            int s = perm_src[idx];
            const float2 hv = *(const float2*)&h[(size_t)s * HID + 2*c];
            uint32 ev = e_sorted[(size_t)idx * 32 + c];
            accx += fmaxf(hv.x + bf_lo(ev), 0.f);
            accy += fmaxf(hv.y + bf_hi(ev), 0.f);
        }
    }
    accx += __shfl_xor(accx, 32);
    accy += __shfl_xor(accy, 32);
    if (half == 0) {
        const float2 hn = *(const float2*)&h[(size_t)node * HID + 2*c];
        float2 res;
        res.x = fmaf(1.1f, hn.x, accx);
        res.y = fmaf(1.1f, hn.y, accy);
        *(float2*)&z[(size_t)node * HID + 2*c] = res;
    }
}

// ---------------- global add pool (batch is sorted) ----------------

__global__ __launch_bounds__(256) void k_pool(
    const float* __restrict__ h, const int* __restrict__ batch, float* __restrict__ out)
{
    int g = blockIdx.x;
    int lane = threadIdx.x & 63, wave = threadIdx.x >> 6;
    int lo = 0, hi = N_NODES;
    while (lo < hi) { int mid = (lo + hi) >> 1; if (batch[mid] < g) lo = mid + 1; else hi = mid; }
    int start = lo;
    hi = N_NODES;
    while (lo < hi) { int mid = (lo + hi) >> 1; if (batch[mid] < g + 1) lo = mid + 1; else hi = mid; }
    int end = lo;
    float acc = 0.f;
    for (int n = start + wave; n < end; n += 4)
        acc += h[(size_t)n*HID + lane];
    __shared__ float sh[4][64];
    sh[wave][lane] = acc;
    __syncthreads();
    if (wave == 0)
        out[(size_t)g*HID + lane] = sh[0][lane] + sh[1][lane] + sh[2][lane] + sh[3][lane];
}

// ---------------- launch ----------------

extern "C" void kernel_launch(void* const* d_in, const int* in_sizes, int n_in,
                              void* d_out, int out_size, void* d_ws, size_t ws_size,
                              hipStream_t stream) {
    const float* x     = (const float*)d_in[0];
    const int*   eidx  = (const int*)  d_in[1];
    const float* eattr = (const float*)d_in[2];
    const int*   batch = (const int*)  d_in[3];
    const float* wn0 = (const float*)d_in[4];  const float* bn0 = (const float*)d_in[5];
    const float* wn1 = (const float*)d_in[6];  const float* bn1 = (const float*)d_in[7];
    const float* we0 = (const float*)d_in[8];  const float* be0 = (const float*)d_in[9];
    const float* we1 = (const float*)d_in[10]; const float* be1 = (const float*)d_in[11];
    const float* cw0 = (const float*)d_in[12]; const float* cb0 = (const float*)d_in[13];
    const float* cw1 = (const float*)d_in[14]; const float* cb1 = (const float*)d_in[15];
    const float* lw0 = (const float*)d_in[16]; const float* lb0 = (const float*)d_in[17];
    const float* lw1 = (const float*)d_in[18]; const float* lb1 = (const float*)d_in[19];
    const int* src = eidx;
    const int* dst = eidx + N_EDGES;

    // workspace layout (~214 MB)
    char* ws = (char*)d_ws;
    size_t off = 0;
    auto alloc = [&](size_t bytes) -> void* {
        void* p = ws + off;
        off = (off + bytes + 255) & ~(size_t)255;
        return p;
    };
    int*   counts   = (int*)  alloc((size_t)N_NODES * 4);
    int*   rowptr   = (int*)  alloc((size_t)(N_NODES + 1) * 4);
    int*   cursor   = (int*)  alloc((size_t)N_NODES * 4);
    int*   bsums    = (int*)  alloc(128 * 4);
    int*   perm_src = (int*)  alloc((size_t)N_EDGES * 4);
    int*   newpos   = (int*)  alloc((size_t)N_EDGES * 4);
    float* wt       = (float*)alloc((size_t)20480 * 4);
    float* hA       = (float*)alloc((size_t)N_NODES * HID * 4);
    float* hB       = (float*)alloc((size_t)N_NODES * HID * 4);
    float* zbuf     = (float*)alloc((size_t)N_NODES * HID * 4);
    uint32* e_sorted = (uint32*)alloc((size_t)N_EDGES * HID * 2);
    if (off > ws_size) {
        k_diag<<<1, 64, 0, stream>>>((float*)d_out, 1.0e9f);
        return;
    }

    // transposed w0-type weights only
    float* wn0t = wt + 0;       // 32*64 = 2048
    float* we0t = wt + 2048;    // 16*64 = 1024
    float* cw0t = wt + 3072;    // 3*4096
    float* lw0t = wt + 15360;   // 4096

    const int NB = (N_NODES + 1023) / 1024;  // 98

    hipMemsetAsync(counts, 0, (size_t)N_NODES * 4, stream);
    k_hist<<<(N_EDGES + 255) / 256, 256, 0, stream>>>(dst, counts);
    k_scan1<<<NB, 256, 0, stream>>>(counts, bsums);
    k_scan2<<<1, 128, 0, stream>>>(bsums, NB);
    k_scan3<<<NB, 256, 0, stream>>>(counts, bsums, rowptr, cursor);
    k_fill<<<(N_EDGES + 255) / 256, 256, 0, stream>>>(src, dst, cursor, perm_src, newpos);

    TransJobs jobs;
    jobs.j[0] = { wn0, wn0t, INN, HID };
    jobs.j[1] = { we0, we0t, INE, HID };
    for (int l = 0; l < 3; l++)
        jobs.j[2 + l] = { cw0 + l * 4096, cw0t + l * 4096, HID, HID };
    jobs.j[5] = { lw0, lw0t, HID, HID };
    k_transpose_all<<<6, 256, 0, stream>>>(jobs);

    const int NGRID = (N_NODES + 255) / 256;  // 391

    k_mlp<INN, false><<<NGRID, 256, 0, stream>>>(x, nullptr, hA, wn0t, bn0, wn1, bn1, N_NODES);

    k_edge_mlp<<<(N_EDGES + 255) / 256, 256, 0, stream>>>(eattr, newpos, e_sorted,
                                                          we0t, be0, we1, be1);

    float* hcur = hA;
    float* hnxt = hB;
    const int AGRID = (N_NODES + 3) / 4;  // 25000
    for (int l = 0; l < 3; l++) {
        k_agg<<<AGRID, 256, 0, stream>>>(hcur, e_sorted, rowptr, perm_src, zbuf);
        k_mlp<HID, true><<<NGRID, 256, 0, stream>>>(zbuf, hcur, hnxt,
                                                    cw0t + l * 4096, cb0 + l * 64,
                                                    cw1 + l * 4096, cb1 + l * 64, N_NODES);
        float* t = hcur; hcur = hnxt; hnxt = t;
    }
    k_agg<<<AGRID, 256, 0, stream>>>(hcur, e_sorted, rowptr, perm_src, zbuf);
    k_mlp<HID, false><<<NGRID, 256, 0, stream>>>(zbuf, nullptr, hnxt,
                                                 lw0t, lb0, lw1, lb1, N_NODES);

    k_pool<<<N_GRAPHS, 256, 0, stream>>>(hnxt, batch, (float*)d_out);
}